// Round 2
// baseline (1590.794 us; speedup 1.0000x reference)
//
#include <hip/hip_runtime.h>

#define NN 20000
#define NE 200000
#define NG 512

constexpr int BN = 16;   // nodes per workgroup
constexpr int EB = 64;   // edges staged per batch

__device__ __forceinline__ int lowerb(const int* a, int n, int v){
  int lo=0, hi=n;
  while(lo<hi){ int m=(lo+hi)>>1; if(a[m]<v) lo=m+1; else hi=m; }
  return lo;
}

// ---------------- sorting (counting sort by tgt -> CSR) ----------------
__global__ void k_count(const int* __restrict__ tgt, int* __restrict__ cnt){
  int e = blockIdx.x*blockDim.x + threadIdx.x;
  if(e<NE) atomicAdd(&cnt[tgt[e]], 1);
}

__global__ void k_scan(const int* __restrict__ cnt, int* __restrict__ row_start){
  __shared__ int part[1024];
  int t = threadIdx.x;
  const int CH = (NN + 1023)/1024; // 20
  int i0 = t*CH;
  int s = 0;
  for(int j=0;j<CH;j++){ int i=i0+j; if(i<NN) s += cnt[i]; }
  part[t] = s; __syncthreads();
  for(int d=1; d<1024; d<<=1){
    int v = (t>=d) ? part[t-d] : 0;
    __syncthreads();
    part[t] += v;
    __syncthreads();
  }
  int run = (t==0) ? 0 : part[t-1];
  for(int j=0;j<CH;j++){ int i=i0+j; if(i<NN){ row_start[i]=run; run += cnt[i]; } }
  if(t==0) row_start[NN] = part[1023];
}

__global__ void k_place(const int* __restrict__ src, const int* __restrict__ tgt,
                        const int* __restrict__ row_start, int* __restrict__ cur,
                        int* __restrict__ es_src, int* __restrict__ es_pos){
  int e = blockIdx.x*blockDim.x + threadIdx.x;
  if(e>=NE) return;
  int n = tgt[e];
  int pos = row_start[n] + atomicAdd(&cur[n],1);
  es_src[pos] = src[e];
  es_pos[e] = pos;
}

// gather edge_attr into CSR order (once) so layer staging is coalesced
__global__ void k_gather(const float* __restrict__ ea, const int* __restrict__ es_pos,
                         float* __restrict__ es_ea){
  int e = blockIdx.x*blockDim.x + threadIdx.x;
  if(e>=NE) return;
  int p = es_pos[e];
  const float4* s = (const float4*)ea + (size_t)e*4;
  float4* d = (float4*)es_ea + (size_t)p*4;
  d[0]=s[0]; d[1]=s[1]; d[2]=s[2]; d[3]=s[3];
}

// ---------------- fused NNConv layer ----------------
// part[split][n][o] = sum_{k in split} S[n,k]*W2[p0*IC+k, o] (+ xbar@b2 on split 0)
// S[n,p,i] = sum_{e in in(n)} relu(ea@W1+b1)[p0+p]/deg(n) * x[src[e], i]
// Scatter accumulators live in REGISTERS (each thread owns (p,i)-tile x all BN nodes);
// staging buffers alias the S LDS region (S only materialized for the GEMM phase).
template<int IC, int OC, int PLEN, int KS, int PP, int TI, int OT, int MINW>
__launch_bounds__(256, MINW)
__global__ void k_layer(const float* __restrict__ x_in,
                        const int* __restrict__ es_src, const float* __restrict__ es_ea,
                        const int* __restrict__ row_start,
                        const float* __restrict__ W1, const float* __restrict__ b1,
                        const float* __restrict__ W2, const float* __restrict__ b2,
                        float* __restrict__ part)
{
  constexpr int K     = PLEN*IC;
  constexpr int KC    = 16;
  constexpr int ITERS = K/(4*KC);
  constexpr int PR    = PLEN/4;
  static_assert(PLEN/PP==16 && IC/TI==16 && OC/OT==16, "tiling");
  static_assert(EB*(IC+16+PLEN+1) <= BN*PLEN*IC, "staging alias fits in S");

  __shared__ __align__(16) float S[BN*PLEN*IC];
  __shared__ float W1s[16*PLEN];
  __shared__ float b1s[PLEN];
  __shared__ float xbar_s[BN*IC];
  __shared__ int rs_s[BN+1];
  __shared__ int ro[BN+1];

  float* xs    = S;                   // EB*IC
  float* eas   = S + EB*IC;           // EB*16
  float* hbuf  = eas + EB*16;         // EB*PLEN
  float* dinvs = hbuf + EB*PLEN;      // EB

  const int tid = threadIdx.x;
  const int split = blockIdx.x % KS;
  const int nb = blockIdx.x / KS;
  const int n0 = nb*BN;
  const int p0 = split*PLEN;

  for(int i=tid;i<16*PLEN;i+=256){ int r=i/PLEN, c=i-r*PLEN; W1s[i]=W1[r*128 + p0 + c]; }
  if(tid<PLEN) b1s[tid]=b1[p0+tid];
  if(tid<=BN) rs_s[tid]=row_start[n0+tid];
  __syncthreads();

  const int estart = rs_s[0], eend = rs_s[BN];

  const int pt = tid>>4, it = tid&15;
  const int ib = it*TI;

  float acc[BN][PP][TI];
  #pragma unroll
  for(int n=0;n<BN;n++)
    #pragma unroll
    for(int p=0;p<PP;p++)
      #pragma unroll
      for(int u=0;u<TI;u++) acc[n][p][u]=0.f;
  float xacc[TI];
  #pragma unroll
  for(int u=0;u<TI;u++) xacc[u]=0.f;

  for(int bstart=estart; bstart<eend; bstart+=EB){
    const int ebc = min(EB, eend-bstart);
    if(tid<=BN){ int v = rs_s[tid]-bstart; ro[tid] = min(max(v,0), ebc); }
    // stage edge_attr (coalesced: es_ea is CSR-ordered)
    for(int j=tid;j<ebc*4;j+=256)
      ((float4*)eas)[j] = ((const float4*)es_ea)[(size_t)bstart*4 + j];
    // stage x[src]
    constexpr int XV = IC/4;
    for(int j=tid;j<ebc*XV;j+=256){
      int e=j/XV, q=j-e*XV;
      int sn=es_src[bstart+e];
      ((float4*)xs)[j] = ((const float4*)x_in)[(size_t)sn*XV + q];
    }
    __syncthreads();
    // edge MLP slice: h~ = relu(ea@W1+b1)[p0:p0+PLEN] / deg
    {
      int e = tid>>2, sub = tid&3;
      if(e < ebc){
        int nl=0;
        while(ro[nl+1]<=e) nl++;
        float deg = (float)(rs_s[nl+1]-rs_s[nl]);
        float dinv = 1.f/fmaxf(deg,1.f);
        if(sub==0) dinvs[e]=dinv;
        float eav[16];
        #pragma unroll
        for(int q=0;q<4;q++){
          float4 v = ((float4*)eas)[e*4+q];
          eav[q*4+0]=v.x; eav[q*4+1]=v.y; eav[q*4+2]=v.z; eav[q*4+3]=v.w;
        }
        #pragma unroll
        for(int r=0;r<PR;r++){
          int p = sub + 4*r;
          float hv = b1s[p];
          #pragma unroll
          for(int i=0;i<16;i++) hv += eav[i]*W1s[i*PLEN+p];
          hbuf[e*PLEN+p] = fmaxf(hv,0.f)*dinv;
        }
      }
    }
    __syncthreads();
    // scatter outer products into REGISTER accumulators
    #pragma unroll
    for(int nl=0;nl<BN;nl++){
      int a=ro[nl], b=ro[nl+1];
      bool duty = (pt==nl);
      for(int e=a;e<b;e++){
        float hv[PP];
        #pragma unroll
        for(int p=0;p<PP;p++) hv[p]=hbuf[e*PLEN + pt*PP + p];
        float dv = dinvs[e];
        #pragma unroll
        for(int u=0;u<TI;u++){
          float xv = xs[e*IC + ib + u];
          #pragma unroll
          for(int p=0;p<PP;p++) acc[nl][p][u] += hv[p]*xv;
          if(duty) xacc[u] += dv*xv;
        }
      }
    }
    __syncthreads();
  }

  // materialize S and xbar in LDS (staging is dead now)
  #pragma unroll
  for(int nl=0;nl<BN;nl++)
    #pragma unroll
    for(int p=0;p<PP;p++)
      #pragma unroll
      for(int u=0;u<TI;u++)
        S[(nl*PLEN + pt*PP + p)*IC + ib + u] = acc[nl][p][u];
  #pragma unroll
  for(int u=0;u<TI;u++) xbar_s[pt*IC + ib + u] = xacc[u];
  __syncthreads();

  // GEMM: thread (og,kc); kc-slice of K, og-slice of OC; reduce-scatter over kc
  const int og = tid>>4, kc = tid&15;
  const int o0 = og*OT;
  float accg[BN][OT];
  #pragma unroll
  for(int n=0;n<BN;n++)
    #pragma unroll
    for(int t=0;t<OT;t++) accg[n][t]=0.f;
  const float* W2p = W2 + (size_t)(p0*IC)*OC + o0;
  for(int itr=0;itr<ITERS;itr++){
    int k = (kc + itr*KC)*4;
    float w[4][OT];
    #pragma unroll
    for(int r=0;r<4;r++)
      #pragma unroll
      for(int t=0;t<OT;t++) w[r][t] = W2p[(size_t)(k+r)*OC + t];
    #pragma unroll
    for(int n=0;n<BN;n++){
      float4 sv = ((float4*)S)[(n*K + k)>>2];
      #pragma unroll
      for(int t=0;t<OT;t++)
        accg[n][t] += sv.x*w[0][t] + sv.y*w[1][t] + sv.z*w[2][t] + sv.w*w[3][t];
    }
  }
  // in-wave reduce-scatter across the 16-lane kc group: lane kc ends with node kc
  #pragma unroll
  for(int half=8; half>=1; half>>=1){
    #pragma unroll
    for(int j=0;j<half;j++)
      #pragma unroll
      for(int t=0;t<OT;t++){
        float lo = accg[j][t], hi = accg[j+half][t];
        float send = (kc&half) ? lo : hi;
        float recv = __shfl_xor(send, half, 64);
        accg[j][t] = (kc&half) ? (hi+recv) : (lo+recv);
      }
  }
  float res[OT];
  #pragma unroll
  for(int t=0;t<OT;t++) res[t]=accg[0][t];
  if(split==0){
    #pragma unroll
    for(int t=0;t<OT;t++){
      float s=0.f;
      for(int i=0;i<IC;i++) s += xbar_s[kc*IC+i]*b2[i*OC + o0 + t];
      res[t]+=s;
    }
  }
  #pragma unroll
  for(int t=0;t<OT;t++)
    part[((size_t)split*NN + n0 + kc)*OC + o0 + t] = res[t];
}

// ---------------- epilogue: y = relu(sum_s part[s] + x@root + bias) ----------------
template<int IC, int OC, int KS>
__global__ void k_epi(const float* __restrict__ part, const float* __restrict__ x,
                      const float* __restrict__ root, const float* __restrict__ bias,
                      float* __restrict__ y)
{
  int idx = blockIdx.x*256 + threadIdx.x;
  if(idx >= NN*OC) return;
  int n = idx/OC, o = idx - n*OC;
  float v = bias[o];
  #pragma unroll
  for(int s=0;s<KS;s++) v += part[(size_t)s*NN*OC + idx];
  #pragma unroll
  for(int i=0;i<IC;i++) v += x[(size_t)n*IC+i]*root[i*OC+o];
  y[idx] = fmaxf(v, 0.f);
}

// ---------------- set2set (2 steps) + final MLP, one wave per graph ----------------
__global__ void k_s2s(const float* __restrict__ xg, const int* __restrict__ batch,
  const float* __restrict__ Wih, const float* __restrict__ Whh,
  const float* __restrict__ bih, const float* __restrict__ bhh,
  const float* __restrict__ l1W, const float* __restrict__ l1b,
  const float* __restrict__ l2W, const float* __restrict__ l2b,
  const float* __restrict__ lfW, const float* __restrict__ lfb,
  float* __restrict__ out)
{
  int g = blockIdx.x, lane = threadIdx.x;
  __shared__ float hs[16], cs[16], qs[32], gs[64], rs[16];
  int r0 = lowerb(batch, NN, g);
  int r1 = lowerb(batch, NN, g+1);
  if(lane<16){ hs[lane]=0.f; cs[lane]=0.f; }
  if(lane<32) qs[lane]=0.f;
  __syncthreads();
  for(int step=0; step<2; step++){
    float gate = bih[lane] + bhh[lane];
    for(int k=0;k<32;k++) gate += qs[k]*Wih[lane*32+k];
    for(int k=0;k<16;k++) gate += hs[k]*Whh[lane*16+k];
    gs[lane] = gate;
    __syncthreads();
    if(lane<16){
      float ig = 1.f/(1.f+expf(-gs[lane]));
      float fg = 1.f/(1.f+expf(-gs[lane+16]));
      float gg = tanhf(gs[lane+32]);
      float og = 1.f/(1.f+expf(-gs[lane+48]));
      float cn = fg*cs[lane] + ig*gg;
      cs[lane] = cn;
      hs[lane] = og*tanhf(cn);
    }
    __syncthreads();
    float m = -1e30f;
    for(int n=r0+lane; n<r1; n+=64){
      float e=0.f;
      for(int k=0;k<16;k++) e += xg[n*16+k]*hs[k];
      m = fmaxf(m, e);
    }
    for(int d=1; d<64; d<<=1) m = fmaxf(m, __shfl_xor(m, d));
    float ssum = 0.f;
    float racc[16];
    #pragma unroll
    for(int k=0;k<16;k++) racc[k]=0.f;
    for(int n=r0+lane; n<r1; n+=64){
      float e=0.f, xv[16];
      #pragma unroll
      for(int k=0;k<16;k++){ xv[k]=xg[n*16+k]; e += xv[k]*hs[k]; }
      float a = expf(e - m);
      ssum += a;
      #pragma unroll
      for(int k=0;k<16;k++) racc[k] += a*xv[k];
    }
    for(int d=1; d<64; d<<=1) ssum += __shfl_xor(ssum, d);
    #pragma unroll
    for(int k=0;k<16;k++)
      for(int d=1; d<64; d<<=1) racc[k] += __shfl_xor(racc[k], d);
    ssum = fmaxf(ssum, 1e-16f);
    if(lane==0){
      #pragma unroll
      for(int k=0;k<16;k++) rs[k] = racc[k]/ssum;
    }
    __syncthreads();
    if(lane<16){ qs[lane]=hs[lane]; qs[16+lane]=rs[lane]; }
    __syncthreads();
  }
  if(lane<16){
    float v = l1b[lane];
    for(int k=0;k<32;k++) v += qs[k]*l1W[k*16+lane];
    gs[lane] = fmaxf(v,0.f);
  }
  __syncthreads();
  if(lane<8){
    float v = l2b[lane];
    for(int k=0;k<16;k++) v += gs[k]*l2W[k*8+lane];
    gs[32+lane] = fmaxf(v,0.f);
  }
  __syncthreads();
  if(lane==0){
    float v = lfb[0];
    for(int k=0;k<8;k++) v += gs[32+k]*lfW[k];
    out[g] = v;
  }
}

extern "C" void kernel_launch(void* const* d_in, const int* in_sizes, int n_in,
                              void* d_out, int out_size, void* d_ws, size_t ws_size,
                              hipStream_t stream) {
  const float* x0   = (const float*)d_in[0];
  const int*   ei   = (const int*)d_in[1];
  const float* ea   = (const float*)d_in[2];
  const int*   batch= (const int*)d_in[3];
  const float* c1W1 = (const float*)d_in[4];  const float* c1b1 = (const float*)d_in[5];
  const float* c1W2 = (const float*)d_in[6];  const float* c1b2 = (const float*)d_in[7];
  const float* c1rt = (const float*)d_in[8];  const float* c1bs = (const float*)d_in[9];
  const float* c2W1 = (const float*)d_in[10]; const float* c2b1 = (const float*)d_in[11];
  const float* c2W2 = (const float*)d_in[12]; const float* c2b2 = (const float*)d_in[13];
  const float* c2rt = (const float*)d_in[14]; const float* c2bs = (const float*)d_in[15];
  const float* c3W1 = (const float*)d_in[16]; const float* c3b1 = (const float*)d_in[17];
  const float* c3W2 = (const float*)d_in[18]; const float* c3b2 = (const float*)d_in[19];
  const float* c3rt = (const float*)d_in[20]; const float* c3bs = (const float*)d_in[21];
  const float* Wih  = (const float*)d_in[22]; const float* Whh  = (const float*)d_in[23];
  const float* bih  = (const float*)d_in[24]; const float* bhh  = (const float*)d_in[25];
  const float* l1W  = (const float*)d_in[26]; const float* l1b  = (const float*)d_in[27];
  const float* l2W  = (const float*)d_in[28]; const float* l2b  = (const float*)d_in[29];
  const float* lfW  = (const float*)d_in[30]; const float* lfb  = (const float*)d_in[31];
  float* out = (float*)d_out;

  const int* src = ei;
  const int* tgt = ei + NE;

  // workspace carve (~44 MB)
  char* w = (char*)d_ws;
  auto carve = [&](size_t bytes)->void*{ void* p = (void*)w; w += (bytes + 255) & ~(size_t)255; return p; };
  int*   row_start = (int*)carve((NN+1)*sizeof(int));
  int*   cur       = (int*)carve(NN*sizeof(int));
  int*   es_src    = (int*)carve(NE*sizeof(int));
  int*   es_pos    = (int*)carve(NE*sizeof(int));
  float* es_ea     = (float*)carve((size_t)NE*16*sizeof(float));
  float* y1   = (float*)carve((size_t)NN*48*sizeof(float));
  float* y2   = (float*)carve((size_t)NN*32*sizeof(float));
  float* y3   = (float*)carve((size_t)NN*16*sizeof(float));
  float* part = (float*)carve((size_t)8*NN*48*sizeof(float)); // max over layers

  // ---- CSR by tgt + ea gather
  hipMemsetAsync(cur, 0, NN*sizeof(int), stream);
  k_count<<<(NE+255)/256, 256, 0, stream>>>(tgt, cur);
  k_scan<<<1, 1024, 0, stream>>>(cur, row_start);
  hipMemsetAsync(cur, 0, NN*sizeof(int), stream);
  k_place<<<(NE+255)/256, 256, 0, stream>>>(src, tgt, row_start, cur, es_src, es_pos);
  k_gather<<<(NE+255)/256, 256, 0, stream>>>(ea, es_pos, es_ea);

  const int NB = NN/BN; // 1250

  // ---- layer 1: IC=16 OC=48, PLEN=32 KS=4; PP=2 TI=1 OT=3; 4 blocks/CU
  k_layer<16,48,32,4, 2,1,3, 4><<<NB*4, 256, 0, stream>>>(x0, es_src, es_ea, row_start, c1W1, c1b1, c1W2, c1b2, part);
  k_epi<16,48,4><<<(NN*48+255)/256, 256, 0, stream>>>(part, x0, c1rt, c1bs, y1);

  // ---- layer 2: IC=48 OC=32, PLEN=16 KS=8; PP=1 TI=3 OT=2; 3 blocks/CU
  k_layer<48,32,16,8, 1,3,2, 3><<<NB*8, 256, 0, stream>>>(y1, es_src, es_ea, row_start, c2W1, c2b1, c2W2, c2b2, part);
  k_epi<48,32,8><<<(NN*32+255)/256, 256, 0, stream>>>(part, y1, c2rt, c2bs, y2);

  // ---- layer 3: IC=32 OC=16, PLEN=16 KS=8; PP=1 TI=2 OT=1; 4 blocks/CU
  k_layer<32,16,16,8, 1,2,1, 4><<<NB*8, 256, 0, stream>>>(y2, es_src, es_ea, row_start, c3W1, c3b1, c3W2, c3b2, part);
  k_epi<32,16,8><<<(NN*16+255)/256, 256, 0, stream>>>(part, y2, c3rt, c3bs, y3);

  // ---- set2set + MLP head
  k_s2s<<<NG, 64, 0, stream>>>(y3, batch, Wih, Whh, bih, bhh, l1W, l1b, l2W, l2b, lfW, lfb, out);
}